// Round 7
// baseline (299.559 us; speedup 1.0000x reference)
//
#include <hip/hip_runtime.h>
#include <hip/hip_fp16.h>
#include <math.h>

#define SCALE 0.125f   // 64^-0.5

typedef _Float16 f16;
typedef __attribute__((ext_vector_type(8))) _Float16 f16x8;
typedef __attribute__((ext_vector_type(4))) float f32x4;
typedef __attribute__((ext_vector_type(16))) float f32x16;

#define MFMA(a, b, c)   __builtin_amdgcn_mfma_f32_16x16x32_f16((a), (b), (c), 0, 0, 0)
#define MFMA32(a, b, c) __builtin_amdgcn_mfma_f32_32x32x16_f16((a), (b), (c), 0, 0, 0)

// 64-f16 rows (128B = 8 granules of 16B), XOR swizzle: granule g of row r
// lives at slot g ^ (r&7)  -> fragment reads are banked.
#define LX(r, qd) (((r) << 6) + ((((qd) ^ ((r) & 7))) << 3))

// C/D row mapping for 32x32 MFMA: row = (e&3) + 8*(e>>2) + 4*hi
#define CROW(e, hi) (((e) & 3) + 8 * ((e) >> 2) + 4 * (hi))

// async global->LDS, 16B/lane; LDS dest = wave-uniform base + lane*16
__device__ __forceinline__ void gll16(const f16* g, f16* l) {
    __builtin_amdgcn_global_load_lds(
        (const __attribute__((address_space(1))) unsigned int*)(g),
        (__attribute__((address_space(3))) unsigned int*)(l),
        16, 0, 0);
}

// manual 16B global load -> VGPR quad; vmcnt retired ONLY by our asm waits.
// volatile + "memory": pins queue order vs gll16 builtins (count coherence).
__device__ __forceinline__ f16x8 gload16(const f16* p) {
    f16x8 r;
    asm volatile("global_load_dwordx4 %0, %1, off" : "=v"(r) : "v"(p) : "memory");
    return r;
}

union U8 { unsigned u[4]; f16x8 v; };

// pack two f32 -> one dword of 2x f16 (round-toward-zero pack)
__device__ __forceinline__ unsigned pkrtz(float a, float b) {
    unsigned r;
    asm("v_cvt_pkrtz_f16_f32 %0, %1, %2" : "=v"(r) : "v"(a), "v"(b));
    return r;
}

// =====================================================================
// split_all: 7 fp32->fp16x2 split segments in one launch (blockIdx.y).
// =====================================================================
struct SplitSeg { const float* src; f16* h; f16* l; float scale; size_t n; };
struct SplitArgs { SplitSeg seg[7]; };

__global__ __launch_bounds__(256) void split_all(SplitArgs a)
{
    SplitSeg s = a.seg[blockIdx.y];
    size_t i4 = ((size_t)blockIdx.x * 256 + threadIdx.x) * 4;
    size_t stride = (size_t)gridDim.x * 256 * 4;
    for (; i4 < s.n; i4 += stride) {
        float4 v = *(const float4*)&s.src[i4];
        float av[4] = {v.x * s.scale, v.y * s.scale, v.z * s.scale, v.w * s.scale};
        f16 hv[4], lv[4];
#pragma unroll
        for (int j = 0; j < 4; ++j) {
            hv[j] = (f16)av[j];
            lv[j] = (f16)(av[j] - (float)hv[j]);
        }
        *(float2*)&s.h[i4] = *(float2*)hv;
        *(float2*)&s.l[i4] = *(float2*)lv;
    }
}

// =====================================================================
// gemm16<AP,BP>: C[M,N] = A @ B^T, fp16-plane decomposition,
// products = AP+BP-1. fp32 accumulate. Tile 128x64, BK=64.
// (unchanged)
// =====================================================================
template <int AP, int BP>
__global__ __launch_bounds__(256) void gemm16(
    const f16* __restrict__ Ah, const f16* __restrict__ Al, size_t Abat,
    const f16* __restrict__ Bh, const f16* __restrict__ Bl, int Bstr, size_t Bbat,
    float* __restrict__ Cf, const float* __restrict__ bias,
    f16* __restrict__ Ch, f16* __restrict__ Cl, int Cpitch,
    f16* __restrict__ Cth, f16* __restrict__ Ctl, int Mt,
    int Nsplit, f16* __restrict__ C2th, int Mt2,
    size_t Cbat, float oscale, int M, int N, int K)
{
    constexpr int NCH = AP * 16 + BP * 8;      // 1KB staging chunks per k-step
    __shared__ __align__(16) f16 Ash[AP][128 * 64];
    __shared__ __align__(16) f16 Bsh[BP][64 * 64];

    const int tid  = threadIdx.x;
    const int z    = blockIdx.z;
    Ah += z * Abat; if (AP == 2) Al += z * Abat;
    Bh += z * Bbat; if (BP == 2) Bl += z * Bbat;
    const int m0   = blockIdx.y * 128;
    const int n0   = blockIdx.x * 64;
    const int w    = tid >> 6;
    const int lane = tid & 63;
    const int wm   = (w >> 1) * 64;
    const int wn   = (w & 1) * 32;
    const int lq   = lane >> 4;
    const int l15  = lane & 15;
    const int sr   = lane >> 3;                // row-in-chunk 0..7
    const int sg   = lane & 7;                 // physical granule slot

    f32x4 acc[4][2];
#pragma unroll
    for (int mi = 0; mi < 4; ++mi)
#pragma unroll
        for (int ni = 0; ni < 2; ++ni) acc[mi][ni] = (f32x4){0.f, 0.f, 0.f, 0.f};

    for (int k0 = 0; k0 < K; k0 += 64) {
        __syncthreads();
#pragma unroll
        for (int c = 0; c < NCH / 4; ++c) {
            int chunk = c * 4 + w;
            const f16* gp; f16* lp;
            if (chunk < AP * 16) {
                int pl = chunk >> 4, sub = chunk & 15;
                int r = sub * 8 + sr;
                int g = sg ^ (r & 7);
                gp = ((AP == 2 && pl) ? Al : Ah) + (size_t)(m0 + r) * K + k0 + g * 8;
                lp = &Ash[pl][sub * 512];
            } else {
                int cb = chunk - AP * 16;
                int pl = cb >> 3, sub = cb & 7;
                int r = sub * 8 + sr;
                int g = sg ^ (r & 7);
                gp = ((BP == 2 && pl) ? Bl : Bh) + (size_t)(n0 + r) * Bstr + k0 + g * 8;
                lp = &Bsh[pl][sub * 512];
            }
            gll16(gp, lp);
        }
        __syncthreads();

#pragma unroll
        for (int kc = 0; kc < 2; ++kc) {
            f16x8 afh[4], afl[4];
#pragma unroll
            for (int mi = 0; mi < 4; ++mi) {
                int r = wm + mi * 16 + l15;
                afh[mi] = *(const f16x8*)&Ash[0][LX(r, kc * 4 + lq)];
                if (AP == 2) afl[mi] = *(const f16x8*)&Ash[1][LX(r, kc * 4 + lq)];
            }
#pragma unroll
            for (int ni = 0; ni < 2; ++ni) {
                int r = wn + ni * 16 + l15;
                f16x8 bh = *(const f16x8*)&Bsh[0][LX(r, kc * 4 + lq)];
                f16x8 bl;
                if (BP == 2) bl = *(const f16x8*)&Bsh[1][LX(r, kc * 4 + lq)];
#pragma unroll
                for (int mi = 0; mi < 4; ++mi) {
                    f32x4 a = acc[mi][ni];
                    a = MFMA(afh[mi], bh, a);
                    if (BP == 2) a = MFMA(afh[mi], bl, a);
                    if (AP == 2) a = MFMA(afl[mi], bh, a);
                    acc[mi][ni] = a;
                }
            }
        }
    }

    const bool vhalf = (Nsplit > 0) && (n0 >= Nsplit);
    if (Cf)  Cf  += z * Cbat;
    if (Ch)  { Ch += z * Cbat; if (Cl) Cl += z * Cbat; }

#pragma unroll
    for (int mi = 0; mi < 4; ++mi) {
#pragma unroll
        for (int ni = 0; ni < 2; ++ni) {
            int row = m0 + wm + mi * 16 + lq * 4;
            int col = n0 + wn + ni * 16 + l15;
            float v[4];
#pragma unroll
            for (int r = 0; r < 4; ++r) v[r] = acc[mi][ni][r] * oscale;
            if (Cf) {
                float bb = bias ? bias[col] : 0.f;
#pragma unroll
                for (int r = 0; r < 4; ++r)
                    Cf[(size_t)(row + r) * Cpitch + col] = v[r] + bb;
            } else if (vhalf) {
                union { f16 a[4]; float2 f; } uh;
#pragma unroll
                for (int r = 0; r < 4; ++r) uh.a[r] = (f16)v[r];
                *(float2*)&C2th[(size_t)(col - Nsplit) * Mt2 + row] = uh.f;
            } else {
                if (Ch) {
#pragma unroll
                    for (int r = 0; r < 4; ++r) {
                        f16 hh = (f16)v[r];
                        Ch[(size_t)(row + r) * Cpitch + col] = hh;
                        if (Cl) Cl[(size_t)(row + r) * Cpitch + col] = (f16)(v[r] - (float)hh);
                    }
                }
                if (Cth) {
                    union { f16 a[4]; float2 f; } uh, ul;
#pragma unroll
                    for (int r = 0; r < 4; ++r) {
                        uh.a[r] = (f16)v[r];
                        ul.a[r] = (f16)(v[r] - (float)uh.a[r]);
                    }
                    *(float2*)&Cth[(size_t)col * Mt + row] = uh.f;
                    if (Ctl) *(float2*)&Ctl[(size_t)col * Mt + row] = ul.f;
                }
            }
        }
    }
}

// =====================================================================
// MFMA fused FCA attention — R6: R5 minus spills, minus V-in-LDS.
// 1) __launch_bounds__(512) plain: R5's (512,4) forced a 64-VGPR budget
//    -> 12MB scratch traffic. Kernel needs ~110 live regs.
// 2) V via direct per-lane global_load_dwordx4 (L2-served): deletes Vsh,
//    the V stage, 4 LDS b128 reads/wave/jt, and ONE barrier per jt.
// vmcnt queue per wave: [KG_cur 3][V 4][KG_nxt 3]
//   top:  issue V(4), stage KG_nxt(3); vmcnt(7) retires KG_cur; barrier
//   QK/FW + per-lane softmax + in-reg P assembly
//   vmcnt(3) retires V (KG_nxt in flight); sched_barrier; PV (reg-only)
//   lgkmcnt(0); barrier  (protect buf[cur] before next stage overwrites)
// Last jt: vmcnt(4) / vmcnt(0).
// =====================================================================
__global__ __launch_bounds__(512) void attn_mfma(
    const f16* __restrict__ Qh, const f16* __restrict__ Ql,
    const f16* __restrict__ Kh,
    const f16* __restrict__ Gh, const f16* __restrict__ Gl,
    const f16* __restrict__ Vth, f16* __restrict__ AOh)
{
    __shared__ __align__(16) f16 Ksh[2][4096];        // K double buffer
    __shared__ __align__(16) f16 Gsh[2][2][4096];     // [buf][plane]
    __shared__ float mxsh[4][2][32];
    __shared__ int eflag[8];

    const int tid = threadIdx.x;
    const int bh = blockIdx.x;            // fast dim -> XCD locality per (b,h)
    const int b = bh >> 4, h = bh & 15;
    const int qr0 = blockIdx.y * 128;
    const int w = tid >> 6, lane = tid & 63;
    const int l31 = lane & 31, hi = lane >> 5;
    const int wq = w >> 1;                // q-tile 0..3 (32 rows each)
    const int wk = w & 1;                 // k-half 0..1 (32 of 64 tile rows)
    const int arow = wk * 32 + l31;       // A-operand row in staged tiles

    const size_t qb = ((size_t)(b * 2048 + qr0)) * 1024 + h * 64;
    const size_t kb = ((size_t)(b * 1024)) * 1024 + h * 64;
    const size_t vb = (size_t)(h * 64) * 2048 + b * 1024;

    const int sr = lane >> 3;
    const int ss = lane & 7;

    // Q B-fragments in registers: lane -> q-col = l31, d = c*16 + hi*8 + j
    f16x8 bqh[4], bql[4];
#pragma unroll
    for (int c = 0; c < 4; ++c) {
        size_t off = qb + (size_t)(wq * 32 + l31) * 1024 + c * 16 + hi * 8;
        bqh[c] = *(const f16x8*)&Qh[off];
        bql[c] = *(const f16x8*)&Ql[off];
    }

    // V B-fragment base: lane reads V^T[d = dt*32+l31][k = (wk*2+lc)*16 + hi*8 ..]
    const f16* vlane = Vth + vb + (size_t)l31 * 2048 + (wk * 2) * 16 + hi * 8;

    // ---------------- pass 1: rowmax of min(|fw|,1), early exit ----------------
    float mxr = 0.f, rowmax = 0.f;
    for (int jt = 0; jt < 16; ++jt) {
        // stage Gh+Gl tile (16 chunks, 2/wave)
#pragma unroll
        for (int c = 0; c < 2; ++c) {
            int chunk = c * 8 + w;
            int pl = chunk >> 3, sub = chunk & 7;
            int r = sub * 8 + sr;
            int g = ss ^ (r & 7);
            gll16((pl ? Gl : Gh) + kb + (size_t)(jt * 64 + r) * 1024 + g * 8,
                  &Gsh[0][pl][sub * 512]);
        }
        __syncthreads();

        f32x16 fw;
#pragma unroll
        for (int e = 0; e < 16; ++e) fw[e] = 0.f;
#pragma unroll
        for (int c = 0; c < 4; ++c) {
            int lx = LX(arow, c * 2 + hi);
            f16x8 agh = *(const f16x8*)&Gsh[0][0][lx];
            f16x8 agl = *(const f16x8*)&Gsh[0][1][lx];
            fw = MFMA32(agh, bqh[c], fw);
            fw = MFMA32(agh, bql[c], fw);
            fw = MFMA32(agl, bqh[c], fw);
        }
#pragma unroll
        for (int e = 0; e < 16; ++e)
            mxr = fmaxf(mxr, fminf(fabsf(fw[e]) * SCALE, 1.f));
        float m2 = fmaxf(mxr, __shfl_xor(mxr, 32, 64));
        if (lane < 32) mxsh[wq][wk][lane] = m2;
        __syncthreads();
        rowmax = fmaxf(m2, mxsh[wq][wk ^ 1][l31]);
        int wd = __all((rowmax >= 1.0f) ? 1 : 0);
        if (lane == 0) eflag[w] = wd;
        __syncthreads();
        bool allw = true;
#pragma unroll
        for (int i = 0; i < 8; ++i) allw = allw && (eflag[i] != 0);
        if (allw) break;
    }
    // per-row |fw_raw| threshold: KEEP iff |fw_raw| > 4.8*(m+1e-6)
    const float T = 4.8f * (rowmax + 1e-6f);

    // ---------------- pass 2: attention (pipelined) ----------------
    const float SL2E = 0.125f * 1.44269504088896f;
    const float PEN2 = -50.0f * 1.44269504088896f;
    f32x16 aco[2];
#pragma unroll
    for (int dt = 0; dt < 2; ++dt)
#pragma unroll
        for (int e = 0; e < 16; ++e) aco[dt][e] = 0.f;
    float dsum = 0.f;

    // KG staging: 24 1KB chunks (K 8 + Gh 8 + Gl 8), 3 per wave
    auto stageKG = [&](int jtn, int buf) {
#pragma unroll
        for (int c = 0; c < 3; ++c) {
            int chunk = c * 8 + w;               // 0..23
            int sub = chunk & 7;
            int r = sub * 8 + sr;
            int g = ss ^ (r & 7);
            size_t off = kb + (size_t)(jtn * 64 + r) * 1024 + g * 8;
            const f16* gp; f16* lp;
            if (chunk < 8)       { gp = Kh + off; lp = &Ksh[buf][sub * 512]; }
            else if (chunk < 16) { gp = Gh + off; lp = &Gsh[buf][0][sub * 512]; }
            else                 { gp = Gl + off; lp = &Gsh[buf][1][sub * 512]; }
            gll16(gp, lp);
        }
    };

    stageKG(0, 0);   // prologue: KG tile 0 in flight (3/wave)

    for (int jt = 0; jt < 16; ++jt) {
        const int cur = jt & 1;

        // issue V[jt] fragment loads -> registers (4/lane, L2-served)
        f16x8 vf[2][2];
#pragma unroll
        for (int dt = 0; dt < 2; ++dt)
#pragma unroll
            for (int lc = 0; lc < 2; ++lc)
                vf[dt][lc] = gload16(vlane + (size_t)dt * 32 * 2048 + jt * 64 + lc * 16);

        if (jt < 15) {
            stageKG(jt + 1, cur ^ 1);
            // outstanding: KG_cur(3) + V(4) + KG_nxt(3) = 10; retire KG_cur
            asm volatile("s_waitcnt vmcnt(7)" ::: "memory");
        } else {
            // outstanding: KG_cur(3) + V(4) = 7; retire KG_cur
            asm volatile("s_waitcnt vmcnt(4)" ::: "memory");
        }
        __builtin_amdgcn_sched_barrier(0);
        __builtin_amdgcn_s_barrier();            // KG[cur] visible to all waves
        __builtin_amdgcn_sched_barrier(0);

        // QK + FW from buf[cur]: D cols = q (lane&31), rows = k_local
        f32x16 s, f;
#pragma unroll
        for (int e = 0; e < 16; ++e) { s[e] = 0.f; f[e] = 0.f; }
        __builtin_amdgcn_s_setprio(1);
#pragma unroll
        for (int c = 0; c < 4; ++c) {
            int lx = LX(arow, c * 2 + hi);
            f16x8 ak  = *(const f16x8*)&Ksh[cur][lx];
            f16x8 agh = *(const f16x8*)&Gsh[cur][0][lx];
            f16x8 agl = *(const f16x8*)&Gsh[cur][1][lx];
            s = MFMA32(ak,  bqh[c], s);
            f = MFMA32(agh, bqh[c], f);
            f = MFMA32(agh, bql[c], f);
            f = MFMA32(agl, bqh[c], f);
        }
        __builtin_amdgcn_s_setprio(0);

        // softmax, per-lane. KEEP (|f|>T) -> pen 0; else PEN2.
#pragma unroll
        for (int e = 0; e < 16; ++e) {
            float pen = (fabsf(f[e]) > T) ? 0.f : PEN2;
            float pe = exp2f(fmaf(s[e], SL2E, pen));
            s[e] = pe;
            dsum += pe;
        }
        // assemble PV A-fragments in registers (k_local = lc*16 + hi*8 + j)
        f16x8 pa[2];
#pragma unroll
        for (int lc = 0; lc < 2; ++lc) {
            unsigned w0 = pkrtz(s[8 * lc + 0], s[8 * lc + 1]);
            unsigned w1 = pkrtz(s[8 * lc + 2], s[8 * lc + 3]);
            unsigned w2 = pkrtz(s[8 * lc + 4], s[8 * lc + 5]);
            unsigned w3 = pkrtz(s[8 * lc + 6], s[8 * lc + 7]);
            unsigned r0 = (unsigned)__shfl_xor((int)(hi ? w0 : w2), 32, 64);
            unsigned r1 = (unsigned)__shfl_xor((int)(hi ? w1 : w3), 32, 64);
            U8 fr;
            fr.u[0] = hi ? r0 : w0;
            fr.u[1] = hi ? r1 : w1;
            fr.u[2] = hi ? w2 : r0;
            fr.u[3] = hi ? w3 : r1;
            pa[lc] = fr.v;
        }

        // retire V loads (KG_nxt stays in flight); PV is register-only
        if (jt < 15) asm volatile("s_waitcnt vmcnt(3)" ::: "memory");
        else         asm volatile("s_waitcnt vmcnt(0)" ::: "memory");
        __builtin_amdgcn_sched_barrier(0);

        __builtin_amdgcn_s_setprio(1);
#pragma unroll
        for (int lc = 0; lc < 2; ++lc) {
#pragma unroll
            for (int dt = 0; dt < 2; ++dt)
                aco[dt] = MFMA32(pa[lc], vf[dt][lc], aco[dt]);
        }
        __builtin_amdgcn_s_setprio(0);

        // all LDS frag reads retired before next stage overwrites buf[cur]
        asm volatile("s_waitcnt lgkmcnt(0)" ::: "memory");
        __builtin_amdgcn_sched_barrier(0);
        __builtin_amdgcn_s_barrier();
        __builtin_amdgcn_sched_barrier(0);
    }

    // ---------------- epilogue: cross-k-half reduce + store ----------------
    float dsum2 = dsum + __shfl_xor(dsum, 32, 64);   // combine hi halves
    float* Osh = (float*)&Gsh[0][0][0];              // 32KB, Gsh reuse
    if (wk == 0) {
#pragma unroll
        for (int dt = 0; dt < 2; ++dt)
#pragma unroll
            for (int e = 0; e < 16; ++e)
                Osh[(wq * 32 + CROW(e, hi)) * 64 + dt * 32 + l31] = aco[dt][e];
        if (lane < 32) mxsh[wq][0][lane] = dsum2;
    }
    __syncthreads();
    if (wk == 1) {
        float inv = 1.0f / (dsum2 + mxsh[wq][0][l31]);
        float iv[16];
#pragma unroll
        for (int e = 0; e < 16; ++e) iv[e] = __shfl(inv, CROW(e, hi), 64);
#pragma unroll
        for (int dt = 0; dt < 2; ++dt)
#pragma unroll
            for (int e = 0; e < 16; ++e) {
                int qq = wq * 32 + CROW(e, hi);
                float o = aco[dt][e] + Osh[qq * 64 + dt * 32 + l31];
                AOh[(size_t)(b * 2048 + qr0 + qq) * 1024 + h * 64 + dt * 32 + l31]
                    = (f16)(o * iv[e]);
            }
    }
}

// =====================================================================
// Orchestration
// =====================================================================
extern "C" void kernel_launch(void* const* d_in, const int* in_sizes, int n_in,
                              void* d_out, int out_size, void* d_ws, size_t ws_size,
                              hipStream_t stream)
{
    const float* x   = (const float*)d_in[0];
    const float* ctx = (const float*)d_in[1];
    const float* fam = (const float*)d_in[2];
    const float* Wq  = (const float*)d_in[3];
    const float* Wk  = (const float*)d_in[4];
    const float* Wv  = (const float*)d_in[5];
    const float* Wo  = (const float*)d_in[6];
    const float* bo  = (const float*)d_in[7];
    float* out = (float*)d_out;

    const size_t nX  = (size_t)4096 * 1024;
    const size_t nC  = (size_t)2048 * 768;
    const size_t nWq = (size_t)1024 * 1024;
    const size_t nWk = (size_t)1024 * 768;
    const size_t nF  = (size_t)1024 * 1024;
    const size_t nK  = (size_t)2048 * 1024;

    char* p = (char*)d_ws;
    f16 *xh   = (f16*)p; p += nX * 2;   f16 *xl   = (f16*)p; p += nX * 2;
    f16 *ch   = (f16*)p; p += nC * 2;   f16 *cl   = (f16*)p; p += nC * 2;
    f16 *wqh  = (f16*)p; p += nWq * 2;  f16 *wql  = (f16*)p; p += nWq * 2;
    f16 *wkvh = (f16*)p; p += nWk * 4;  f16 *wkvl = (f16*)p; p += nWk * 4;  // [Wk;Wv]
    f16 *woh  = (f16*)p; p += nWq * 2;  f16 *wol  = (f16*)p; p += nWq * 2;
    f16 *fmh  = (f16*)p; p += nF * 2;   f16 *fml  = (f16*)p; p += nF * 2;
    f16 *qh   = (f16*)p; p += nX * 2;   f16 *ql   = (f16*)p; p += nX * 2;
    f16 *kh   = (f16*)p; p += nK * 2;
    f16 *kth  = (f16*)p; p += nK * 2;   f16 *ktl  = (f16*)p; p += nK * 2;
    f16 *vth  = (f16*)p; p += nK * 2;
    f16 *gh   = (f16*)p; p += nK * 2;   f16 *gl   = (f16*)p; p += nK * 2;
    f16 *aoh  = (f16*)p; p += nX * 2;

    const float WS  = 64.0f;       // weight pre-scale (exact pow2)
    const float IWS = 1.0f / 64.0f;

    SplitArgs sa;
    sa.seg[0] = {x,   xh,          xl,          1.f, nX};
    sa.seg[1] = {ctx, ch,          cl,          1.f, nC};
    sa.seg[2] = {Wq,  wqh,         wql,         WS,  nWq};
    sa.seg[3] = {Wk,  wkvh,        wkvl,        WS,  nWk};
    sa.seg[4] = {Wv,  wkvh + nWk,  wkvl + nWk,  WS,  nWk};
    sa.seg[5] = {Wo,  woh,         wol,         WS,  nWq};
    sa.seg[6] = {fam, fmh,         fml,         1.f, nF};
    split_all<<<dim3(64, 7), 256, 0, stream>>>(sa);

    // q = x @ Wq^T : row-major fp16x2 planes (512 blocks, 2/CU)
    gemm16<2, 2><<<dim3(16, 32, 1), 256, 0, stream>>>(
        xh, xl, 0, wqh, wql, 1024, 0,
        nullptr, nullptr, qh, ql, 1024, nullptr, nullptr, 0,
        0, nullptr, 0, 0, IWS, 4096, 1024, 1024);

    // [k|v] = ctx @ [Wk|Wv]^T in one launch (N=2048, 512 blocks).
    gemm16<2, 2><<<dim3(32, 16, 1), 256, 0, stream>>>(
        ch, cl, 0, wkvh, wkvl, 768, 0,
        nullptr, nullptr, kh, nullptr, 1024, kth, ktl, 2048,
        1024, vth, 2048, 0, IWS, 2048, 2048, 768);

    // G_b = fam @ k_b (B = transposed-k planes, batch via z)
    gemm16<2, 2><<<dim3(16, 8, 2), 256, 0, stream>>>(
        fmh, fml, 0, kth, ktl, 2048, 1024,
        nullptr, nullptr, gh, gl, 1024, nullptr, nullptr, 0,
        0, nullptr, 0, (size_t)1024 * 1024, 1.f, 1024, 1024, 1024);

    // fused FCA attention -> single fp16 ao plane (512 blocks x 8 waves)
    attn_mfma<<<dim3(32, 16), 512, 0, stream>>>(qh, ql, kh, gh, gl, vth, aoh);

    // out = ao @ Wo^T + bo (single-plane 1-product GEMM)
    gemm16<1, 1><<<dim3(16, 32, 1), 256, 0, stream>>>(
        aoh, nullptr, 0, woh, nullptr, 1024, 0,
        out, bo, nullptr, nullptr, 1024, nullptr, nullptr, 0,
        0, nullptr, 0, 0, IWS, 4096, 1024, 1024);
}

// Round 8
// 269.860 us; speedup vs baseline: 1.1101x; 1.1101x over previous
//
#include <hip/hip_runtime.h>
#include <hip/hip_fp16.h>
#include <math.h>

#define SCALE 0.125f   // 64^-0.5

typedef _Float16 f16;
typedef __attribute__((ext_vector_type(8))) _Float16 f16x8;
typedef __attribute__((ext_vector_type(4))) float f32x4;
typedef __attribute__((ext_vector_type(16))) float f32x16;

#define MFMA(a, b, c)   __builtin_amdgcn_mfma_f32_16x16x32_f16((a), (b), (c), 0, 0, 0)
#define MFMA32(a, b, c) __builtin_amdgcn_mfma_f32_32x32x16_f16((a), (b), (c), 0, 0, 0)

// 64-f16 rows (128B = 8 granules of 16B), XOR swizzle: granule g of row r
// lives at slot g ^ (r&7)  -> fragment reads are banked.
#define LX(r, qd) (((r) << 6) + ((((qd) ^ ((r) & 7))) << 3))

// C/D row mapping for 32x32 MFMA: row = (e&3) + 8*(e>>2) + 4*hi
#define CROW(e, hi) (((e) & 3) + 8 * ((e) >> 2) + 4 * (hi))

// async global->LDS, 16B/lane; LDS dest = wave-uniform base + lane*16
__device__ __forceinline__ void gll16(const f16* g, f16* l) {
    __builtin_amdgcn_global_load_lds(
        (const __attribute__((address_space(1))) unsigned int*)(g),
        (__attribute__((address_space(3))) unsigned int*)(l),
        16, 0, 0);
}

union U8 { unsigned u[4]; f16x8 v; };

// pack two f32 -> one dword of 2x f16 (round-toward-zero pack)
__device__ __forceinline__ unsigned pkrtz(float a, float b) {
    unsigned r;
    asm("v_cvt_pkrtz_f16_f32 %0, %1, %2" : "=v"(r) : "v"(a), "v"(b));
    return r;
}

// =====================================================================
// split_all: 7 fp32->fp16x2 split segments in one launch (blockIdx.y).
// =====================================================================
struct SplitSeg { const float* src; f16* h; f16* l; float scale; size_t n; };
struct SplitArgs { SplitSeg seg[7]; };

__global__ __launch_bounds__(256) void split_all(SplitArgs a)
{
    SplitSeg s = a.seg[blockIdx.y];
    size_t i4 = ((size_t)blockIdx.x * 256 + threadIdx.x) * 4;
    size_t stride = (size_t)gridDim.x * 256 * 4;
    for (; i4 < s.n; i4 += stride) {
        float4 v = *(const float4*)&s.src[i4];
        float av[4] = {v.x * s.scale, v.y * s.scale, v.z * s.scale, v.w * s.scale};
        f16 hv[4], lv[4];
#pragma unroll
        for (int j = 0; j < 4; ++j) {
            hv[j] = (f16)av[j];
            lv[j] = (f16)(av[j] - (float)hv[j]);
        }
        *(float2*)&s.h[i4] = *(float2*)hv;
        *(float2*)&s.l[i4] = *(float2*)lv;
    }
}

// =====================================================================
// gemm16<AP,BP>: C[M,N] = A @ B^T, fp16-plane decomposition,
// products = AP+BP-1. fp32 accumulate. Tile 128x64, BK=64.
// (unchanged)
// =====================================================================
template <int AP, int BP>
__global__ __launch_bounds__(256) void gemm16(
    const f16* __restrict__ Ah, const f16* __restrict__ Al, size_t Abat,
    const f16* __restrict__ Bh, const f16* __restrict__ Bl, int Bstr, size_t Bbat,
    float* __restrict__ Cf, const float* __restrict__ bias,
    f16* __restrict__ Ch, f16* __restrict__ Cl, int Cpitch,
    f16* __restrict__ Cth, f16* __restrict__ Ctl, int Mt,
    int Nsplit, f16* __restrict__ C2th, int Mt2,
    size_t Cbat, float oscale, int M, int N, int K)
{
    constexpr int NCH = AP * 16 + BP * 8;      // 1KB staging chunks per k-step
    __shared__ __align__(16) f16 Ash[AP][128 * 64];
    __shared__ __align__(16) f16 Bsh[BP][64 * 64];

    const int tid  = threadIdx.x;
    const int z    = blockIdx.z;
    Ah += z * Abat; if (AP == 2) Al += z * Abat;
    Bh += z * Bbat; if (BP == 2) Bl += z * Bbat;
    const int m0   = blockIdx.y * 128;
    const int n0   = blockIdx.x * 64;
    const int w    = tid >> 6;
    const int lane = tid & 63;
    const int wm   = (w >> 1) * 64;
    const int wn   = (w & 1) * 32;
    const int lq   = lane >> 4;
    const int l15  = lane & 15;
    const int sr   = lane >> 3;                // row-in-chunk 0..7
    const int sg   = lane & 7;                 // physical granule slot

    f32x4 acc[4][2];
#pragma unroll
    for (int mi = 0; mi < 4; ++mi)
#pragma unroll
        for (int ni = 0; ni < 2; ++ni) acc[mi][ni] = (f32x4){0.f, 0.f, 0.f, 0.f};

    for (int k0 = 0; k0 < K; k0 += 64) {
        __syncthreads();
#pragma unroll
        for (int c = 0; c < NCH / 4; ++c) {
            int chunk = c * 4 + w;
            const f16* gp; f16* lp;
            if (chunk < AP * 16) {
                int pl = chunk >> 4, sub = chunk & 15;
                int r = sub * 8 + sr;
                int g = sg ^ (r & 7);
                gp = ((AP == 2 && pl) ? Al : Ah) + (size_t)(m0 + r) * K + k0 + g * 8;
                lp = &Ash[pl][sub * 512];
            } else {
                int cb = chunk - AP * 16;
                int pl = cb >> 3, sub = cb & 7;
                int r = sub * 8 + sr;
                int g = sg ^ (r & 7);
                gp = ((BP == 2 && pl) ? Bl : Bh) + (size_t)(n0 + r) * Bstr + k0 + g * 8;
                lp = &Bsh[pl][sub * 512];
            }
            gll16(gp, lp);
        }
        __syncthreads();

#pragma unroll
        for (int kc = 0; kc < 2; ++kc) {
            f16x8 afh[4], afl[4];
#pragma unroll
            for (int mi = 0; mi < 4; ++mi) {
                int r = wm + mi * 16 + l15;
                afh[mi] = *(const f16x8*)&Ash[0][LX(r, kc * 4 + lq)];
                if (AP == 2) afl[mi] = *(const f16x8*)&Ash[1][LX(r, kc * 4 + lq)];
            }
#pragma unroll
            for (int ni = 0; ni < 2; ++ni) {
                int r = wn + ni * 16 + l15;
                f16x8 bh = *(const f16x8*)&Bsh[0][LX(r, kc * 4 + lq)];
                f16x8 bl;
                if (BP == 2) bl = *(const f16x8*)&Bsh[1][LX(r, kc * 4 + lq)];
#pragma unroll
                for (int mi = 0; mi < 4; ++mi) {
                    f32x4 a = acc[mi][ni];
                    a = MFMA(afh[mi], bh, a);
                    if (BP == 2) a = MFMA(afh[mi], bl, a);
                    if (AP == 2) a = MFMA(afl[mi], bh, a);
                    acc[mi][ni] = a;
                }
            }
        }
    }

    const bool vhalf = (Nsplit > 0) && (n0 >= Nsplit);
    if (Cf)  Cf  += z * Cbat;
    if (Ch)  { Ch += z * Cbat; if (Cl) Cl += z * Cbat; }

#pragma unroll
    for (int mi = 0; mi < 4; ++mi) {
#pragma unroll
        for (int ni = 0; ni < 2; ++ni) {
            int row = m0 + wm + mi * 16 + lq * 4;
            int col = n0 + wn + ni * 16 + l15;
            float v[4];
#pragma unroll
            for (int r = 0; r < 4; ++r) v[r] = acc[mi][ni][r] * oscale;
            if (Cf) {
                float bb = bias ? bias[col] : 0.f;
#pragma unroll
                for (int r = 0; r < 4; ++r)
                    Cf[(size_t)(row + r) * Cpitch + col] = v[r] + bb;
            } else if (vhalf) {
                union { f16 a[4]; float2 f; } uh;
#pragma unroll
                for (int r = 0; r < 4; ++r) uh.a[r] = (f16)v[r];
                *(float2*)&C2th[(size_t)(col - Nsplit) * Mt2 + row] = uh.f;
            } else {
                if (Ch) {
#pragma unroll
                    for (int r = 0; r < 4; ++r) {
                        f16 hh = (f16)v[r];
                        Ch[(size_t)(row + r) * Cpitch + col] = hh;
                        if (Cl) Cl[(size_t)(row + r) * Cpitch + col] = (f16)(v[r] - (float)hh);
                    }
                }
                if (Cth) {
                    union { f16 a[4]; float2 f; } uh, ul;
#pragma unroll
                    for (int r = 0; r < 4; ++r) {
                        uh.a[r] = (f16)v[r];
                        ul.a[r] = (f16)(v[r] - (float)uh.a[r]);
                    }
                    *(float2*)&Cth[(size_t)col * Mt + row] = uh.f;
                    if (Ctl) *(float2*)&Ctl[(size_t)col * Mt + row] = ul.f;
                }
            }
        }
    }
}

// =====================================================================
// MFMA fused FCA attention — R7: R5 structure (swapped 32x32, in-reg P,
// V staged in LDS) + plain __launch_bounds__(512) (R5's (512,4) caused
// 12MB spill; R6 proved plain bounds don't spill) + V double-buffered so
// ALL of tile jt+1 (K+Gh+Gl+V = 32 chunks, 4/wave) stages in one burst:
//   2 barriers/jt (was 3), one wait point.
// vmcnt queue per wave: [KGV_cur 4][KGV_nxt 4]
//   top:  stage KGV[jt+1] (4/wave); vmcnt(4) retires KGV_cur; barrier
//   QK/FW MFMA + per-lane softmax + in-reg P assembly + PV (all LDS
//   reads from buf[cur])
//   lgkmcnt(0); barrier   (protect buf[cur] for the jt+2 stage)
// Last jt: vmcnt(0). Never 0 mid-loop otherwise.
// R6 lesson: V per-lane global loads are 4KB-strided (uncoalesced, 64
// lines/instr) -> keep V in LDS via coalesced row staging.
// =====================================================================
__global__ __launch_bounds__(512) void attn_mfma(
    const f16* __restrict__ Qh, const f16* __restrict__ Ql,
    const f16* __restrict__ Kh,
    const f16* __restrict__ Gh, const f16* __restrict__ Gl,
    const f16* __restrict__ Vth, f16* __restrict__ AOh)
{
    __shared__ __align__(16) f16 Ksh[2][4096];        // K double buffer
    __shared__ __align__(16) f16 Gsh[2][2][4096];     // [buf][plane]
    __shared__ __align__(16) f16 Vsh[2][4096];        // V double buffer
    __shared__ float mxsh[4][2][32];
    __shared__ int eflag[8];

    const int tid = threadIdx.x;
    const int bh = blockIdx.x;            // fast dim -> XCD locality per (b,h)
    const int b = bh >> 4, h = bh & 15;
    const int qr0 = blockIdx.y * 128;
    const int w = tid >> 6, lane = tid & 63;
    const int l31 = lane & 31, hi = lane >> 5;
    const int wq = w >> 1;                // q-tile 0..3 (32 rows each)
    const int wk = w & 1;                 // k-half 0..1 (32 of 64 tile rows)
    const int arow = wk * 32 + l31;       // A-operand row in staged tiles

    const size_t qb = ((size_t)(b * 2048 + qr0)) * 1024 + h * 64;
    const size_t kb = ((size_t)(b * 1024)) * 1024 + h * 64;
    const size_t vb = (size_t)(h * 64) * 2048 + b * 1024;

    const int sr = lane >> 3;
    const int ss = lane & 7;

    // Q B-fragments in registers: lane -> q-col = l31, d = c*16 + hi*8 + j
    f16x8 bqh[4], bql[4];
#pragma unroll
    for (int c = 0; c < 4; ++c) {
        size_t off = qb + (size_t)(wq * 32 + l31) * 1024 + c * 16 + hi * 8;
        bqh[c] = *(const f16x8*)&Qh[off];
        bql[c] = *(const f16x8*)&Ql[off];
    }

    // ---------------- pass 1: rowmax of min(|fw|,1), early exit ----------------
    float mxr = 0.f, rowmax = 0.f;
    for (int jt = 0; jt < 16; ++jt) {
        // stage Gh+Gl tile (16 chunks, 2/wave)
#pragma unroll
        for (int c = 0; c < 2; ++c) {
            int chunk = c * 8 + w;
            int pl = chunk >> 3, sub = chunk & 7;
            int r = sub * 8 + sr;
            int g = ss ^ (r & 7);
            gll16((pl ? Gl : Gh) + kb + (size_t)(jt * 64 + r) * 1024 + g * 8,
                  &Gsh[0][pl][sub * 512]);
        }
        __syncthreads();

        f32x16 fw;
#pragma unroll
        for (int e = 0; e < 16; ++e) fw[e] = 0.f;
#pragma unroll
        for (int c = 0; c < 4; ++c) {
            int lx = LX(arow, c * 2 + hi);
            f16x8 agh = *(const f16x8*)&Gsh[0][0][lx];
            f16x8 agl = *(const f16x8*)&Gsh[0][1][lx];
            fw = MFMA32(agh, bqh[c], fw);
            fw = MFMA32(agh, bql[c], fw);
            fw = MFMA32(agl, bqh[c], fw);
        }
#pragma unroll
        for (int e = 0; e < 16; ++e)
            mxr = fmaxf(mxr, fminf(fabsf(fw[e]) * SCALE, 1.f));
        float m2 = fmaxf(mxr, __shfl_xor(mxr, 32, 64));
        if (lane < 32) mxsh[wq][wk][lane] = m2;
        __syncthreads();
        rowmax = fmaxf(m2, mxsh[wq][wk ^ 1][l31]);
        int wd = __all((rowmax >= 1.0f) ? 1 : 0);
        if (lane == 0) eflag[w] = wd;
        __syncthreads();
        bool allw = true;
#pragma unroll
        for (int i = 0; i < 8; ++i) allw = allw && (eflag[i] != 0);
        if (allw) break;
    }
    // per-row |fw_raw| threshold: KEEP iff |fw_raw| > 4.8*(m+1e-6)
    const float T = 4.8f * (rowmax + 1e-6f);

    // ---------------- pass 2: attention (pipelined) ----------------
    const float SL2E = 0.125f * 1.44269504088896f;
    const float PEN2 = -50.0f * 1.44269504088896f;
    f32x16 aco[2];
#pragma unroll
    for (int dt = 0; dt < 2; ++dt)
#pragma unroll
        for (int e = 0; e < 16; ++e) aco[dt][e] = 0.f;
    float dsum = 0.f;

    // KGV staging: 32 1KB chunks (K 8 + Gh 8 + Gl 8 + V 8), 4 per wave
    auto stageKGV = [&](int jtn, int buf) {
#pragma unroll
        for (int c = 0; c < 4; ++c) {
            int chunk = c * 8 + w;               // 0..31
            int sub = chunk & 7;
            int r = sub * 8 + sr;
            int g = ss ^ (r & 7);
            const f16* gp; f16* lp;
            if (chunk < 24) {
                size_t off = kb + (size_t)(jtn * 64 + r) * 1024 + g * 8;
                if (chunk < 8)       { gp = Kh + off; lp = &Ksh[buf][sub * 512]; }
                else if (chunk < 16) { gp = Gh + off; lp = &Gsh[buf][0][sub * 512]; }
                else                 { gp = Gl + off; lp = &Gsh[buf][1][sub * 512]; }
            } else {
                gp = Vth + vb + (size_t)r * 2048 + jtn * 64 + g * 8;
                lp = &Vsh[buf][sub * 512];
            }
            gll16(gp, lp);
        }
    };

    stageKGV(0, 0);   // prologue: tile 0 in flight (4/wave)

    for (int jt = 0; jt < 16; ++jt) {
        const int cur = jt & 1;

        if (jt < 15) {
            stageKGV(jt + 1, cur ^ 1);
            // outstanding: KGV_cur(4) + KGV_nxt(4) = 8; retire KGV_cur
            asm volatile("s_waitcnt vmcnt(4)" ::: "memory");
        } else {
            // outstanding: KGV_cur(4); retire all
            asm volatile("s_waitcnt vmcnt(0)" ::: "memory");
        }
        __builtin_amdgcn_sched_barrier(0);
        __builtin_amdgcn_s_barrier();            // tile cur visible to all waves
        __builtin_amdgcn_sched_barrier(0);

        // QK + FW from buf[cur]: D cols = q (lane&31), rows = k_local
        f32x16 s, f;
#pragma unroll
        for (int e = 0; e < 16; ++e) { s[e] = 0.f; f[e] = 0.f; }
        __builtin_amdgcn_s_setprio(1);
#pragma unroll
        for (int c = 0; c < 4; ++c) {
            int lx = LX(arow, c * 2 + hi);
            f16x8 ak  = *(const f16x8*)&Ksh[cur][lx];
            f16x8 agh = *(const f16x8*)&Gsh[cur][0][lx];
            f16x8 agl = *(const f16x8*)&Gsh[cur][1][lx];
            s = MFMA32(ak,  bqh[c], s);
            f = MFMA32(agh, bqh[c], f);
            f = MFMA32(agh, bql[c], f);
            f = MFMA32(agl, bqh[c], f);
        }
        __builtin_amdgcn_s_setprio(0);

        // softmax, per-lane. KEEP (|f|>T) -> pen 0; else PEN2.
#pragma unroll
        for (int e = 0; e < 16; ++e) {
            float pen = (fabsf(f[e]) > T) ? 0.f : PEN2;
            float pe = exp2f(fmaf(s[e], SL2E, pen));
            s[e] = pe;
            dsum += pe;
        }
        // assemble PV A-fragments in registers (k_local = lc*16 + hi*8 + j)
        f16x8 pa[2];
#pragma unroll
        for (int lc = 0; lc < 2; ++lc) {
            unsigned w0 = pkrtz(s[8 * lc + 0], s[8 * lc + 1]);
            unsigned w1 = pkrtz(s[8 * lc + 2], s[8 * lc + 3]);
            unsigned w2 = pkrtz(s[8 * lc + 4], s[8 * lc + 5]);
            unsigned w3 = pkrtz(s[8 * lc + 6], s[8 * lc + 7]);
            unsigned r0 = (unsigned)__shfl_xor((int)(hi ? w0 : w2), 32, 64);
            unsigned r1 = (unsigned)__shfl_xor((int)(hi ? w1 : w3), 32, 64);
            U8 fr;
            fr.u[0] = hi ? r0 : w0;
            fr.u[1] = hi ? r1 : w1;
            fr.u[2] = hi ? w2 : r0;
            fr.u[3] = hi ? w3 : r1;
            pa[lc] = fr.v;
        }

        // PV: aco[dt] += P(32q x 16k) x V(32d x 16k), V from buf[cur]
        __builtin_amdgcn_s_setprio(1);
#pragma unroll
        for (int lc = 0; lc < 2; ++lc) {
#pragma unroll
            for (int dt = 0; dt < 2; ++dt) {
                f16x8 bv = *(const f16x8*)&Vsh[cur][LX(dt * 32 + l31, (wk * 2 + lc) * 2 + hi)];
                aco[dt] = MFMA32(pa[lc], bv, aco[dt]);
            }
        }
        __builtin_amdgcn_s_setprio(0);

        // all LDS reads of buf[cur] retired before jt+2's stage overwrites it
        asm volatile("s_waitcnt lgkmcnt(0)" ::: "memory");
        __builtin_amdgcn_sched_barrier(0);
        __builtin_amdgcn_s_barrier();
        __builtin_amdgcn_sched_barrier(0);
    }

    // ---------------- epilogue: cross-k-half reduce + store ----------------
    float dsum2 = dsum + __shfl_xor(dsum, 32, 64);   // combine hi halves
    float* Osh = (float*)&Gsh[0][0][0];              // 32KB, Gsh reuse
    if (wk == 0) {
#pragma unroll
        for (int dt = 0; dt < 2; ++dt)
#pragma unroll
            for (int e = 0; e < 16; ++e)
                Osh[(wq * 32 + CROW(e, hi)) * 64 + dt * 32 + l31] = aco[dt][e];
        if (lane < 32) mxsh[wq][0][lane] = dsum2;
    }
    __syncthreads();
    if (wk == 1) {
        float inv = 1.0f / (dsum2 + mxsh[wq][0][l31]);
        float iv[16];
#pragma unroll
        for (int e = 0; e < 16; ++e) iv[e] = __shfl(inv, CROW(e, hi), 64);
#pragma unroll
        for (int dt = 0; dt < 2; ++dt)
#pragma unroll
            for (int e = 0; e < 16; ++e) {
                int qq = wq * 32 + CROW(e, hi);
                float o = aco[dt][e] + Osh[qq * 64 + dt * 32 + l31];
                AOh[(size_t)(b * 2048 + qr0 + qq) * 1024 + h * 64 + dt * 32 + l31]
                    = (f16)(o * iv[e]);
            }
    }
}

// =====================================================================
// Orchestration
// =====================================================================
extern "C" void kernel_launch(void* const* d_in, const int* in_sizes, int n_in,
                              void* d_out, int out_size, void* d_ws, size_t ws_size,
                              hipStream_t stream)
{
    const float* x   = (const float*)d_in[0];
    const float* ctx = (const float*)d_in[1];
    const float* fam = (const float*)d_in[2];
    const float* Wq  = (const float*)d_in[3];
    const float* Wk  = (const float*)d_in[4];
    const float* Wv  = (const float*)d_in[5];
    const float* Wo  = (const float*)d_in[6];
    const float* bo  = (const float*)d_in[7];
    float* out = (float*)d_out;

    const size_t nX  = (size_t)4096 * 1024;
    const size_t nC  = (size_t)2048 * 768;
    const size_t nWq = (size_t)1024 * 1024;
    const size_t nWk = (size_t)1024 * 768;
    const size_t nF  = (size_t)1024 * 1024;
    const size_t nK  = (size_t)2048 * 1024;

    char* p = (char*)d_ws;
    f16 *xh   = (f16*)p; p += nX * 2;   f16 *xl   = (f16*)p; p += nX * 2;
    f16 *ch   = (f16*)p; p += nC * 2;   f16 *cl   = (f16*)p; p += nC * 2;
    f16 *wqh  = (f16*)p; p += nWq * 2;  f16 *wql  = (f16*)p; p += nWq * 2;
    f16 *wkvh = (f16*)p; p += nWk * 4;  f16 *wkvl = (f16*)p; p += nWk * 4;  // [Wk;Wv]
    f16 *woh  = (f16*)p; p += nWq * 2;  f16 *wol  = (f16*)p; p += nWq * 2;
    f16 *fmh  = (f16*)p; p += nF * 2;   f16 *fml  = (f16*)p; p += nF * 2;
    f16 *qh   = (f16*)p; p += nX * 2;   f16 *ql   = (f16*)p; p += nX * 2;
    f16 *kh   = (f16*)p; p += nK * 2;
    f16 *kth  = (f16*)p; p += nK * 2;   f16 *ktl  = (f16*)p; p += nK * 2;
    f16 *vth  = (f16*)p; p += nK * 2;
    f16 *gh   = (f16*)p; p += nK * 2;   f16 *gl   = (f16*)p; p += nK * 2;
    f16 *aoh  = (f16*)p; p += nX * 2;

    const float WS  = 64.0f;       // weight pre-scale (exact pow2)
    const float IWS = 1.0f / 64.0f;

    SplitArgs sa;
    sa.seg[0] = {x,   xh,          xl,          1.f, nX};
    sa.seg[1] = {ctx, ch,          cl,          1.f, nC};
    sa.seg[2] = {Wq,  wqh,         wql,         WS,  nWq};
    sa.seg[3] = {Wk,  wkvh,        wkvl,        WS,  nWk};
    sa.seg[4] = {Wv,  wkvh + nWk,  wkvl + nWk,  WS,  nWk};
    sa.seg[5] = {Wo,  woh,         wol,         WS,  nWq};
    sa.seg[6] = {fam, fmh,         fml,         1.f, nF};
    split_all<<<dim3(64, 7), 256, 0, stream>>>(sa);

    // q = x @ Wq^T : row-major fp16x2 planes (512 blocks, 2/CU)
    gemm16<2, 2><<<dim3(16, 32, 1), 256, 0, stream>>>(
        xh, xl, 0, wqh, wql, 1024, 0,
        nullptr, nullptr, qh, ql, 1024, nullptr, nullptr, 0,
        0, nullptr, 0, 0, IWS, 4096, 1024, 1024);

    // [k|v] = ctx @ [Wk|Wv]^T in one launch (N=2048, 512 blocks).
    gemm16<2, 2><<<dim3(32, 16, 1), 256, 0, stream>>>(
        ch, cl, 0, wkvh, wkvl, 768, 0,
        nullptr, nullptr, kh, nullptr, 1024, kth, ktl, 2048,
        1024, vth, 2048, 0, IWS, 2048, 2048, 768);

    // G_b = fam @ k_b (B = transposed-k planes, batch via z)
    gemm16<2, 2><<<dim3(16, 8, 2), 256, 0, stream>>>(
        fmh, fml, 0, kth, ktl, 2048, 1024,
        nullptr, nullptr, gh, gl, 1024, nullptr, nullptr, 0,
        0, nullptr, 0, (size_t)1024 * 1024, 1.f, 1024, 1024, 1024);

    // fused FCA attention -> single fp16 ao plane (512 blocks x 8 waves)
    attn_mfma<<<dim3(32, 16), 512, 0, stream>>>(qh, ql, kh, gh, gl, vth, aoh);

    // out = ao @ Wo^T + bo (single-plane 1-product GEMM)
    gemm16<1, 1><<<dim3(16, 32, 1), 256, 0, stream>>>(
        aoh, nullptr, 0, woh, nullptr, 1024, 0,
        out, bo, nullptr, nullptr, 1024, nullptr, nullptr, 0,
        0, nullptr, 0, 0, IWS, 4096, 1024, 1024);
}